// Round 6
// baseline (266.842 us; speedup 1.0000x reference)
//
#include <hip/hip_runtime.h>

// MultiheadAttention N=4096, d_model=512, 8 heads, d_head=64.
// fp32 inputs/output, f16 MFMA pipeline. 3-kernel pipeline:
//  qkv_mask: QKV GEMMs reading fp32 directly (inline cvt_pkrtz in reg-staged
//   swizzled LDS staging, next-tile prefetch under MFMA) + mask bitpack merged
//   as extra grid-z blocks (64MB mask read hides under latency-bound GEMM);
//  attn: split-KV flash attention (unchanged, verified);
//  out_gemm: fused split-KV reduce on A-side + inline fp32 W convert on B-side.

typedef __attribute__((ext_vector_type(8))) _Float16 f16x8;
typedef __attribute__((ext_vector_type(2))) __fp16 fp16x2_raw;  // cvt_pkrtz ret
typedef __attribute__((ext_vector_type(4))) float f32x4;

union pku_t { unsigned u[4]; f16x8 v; };

#define N_TOK 4096
#define QSCALE 0.18033688f  // 0.125 * log2(e)

__device__ __forceinline__ unsigned short f2h(float f) {
  union { _Float16 h; unsigned short u; } c;
  c.h = (_Float16)f;
  return c.u;
}
// packed f32x2 -> f16x2 in ONE instruction (v_cvt_pkrtz_f16_f32).
__device__ __forceinline__ unsigned pack_f16(float a, float b) {
  union { fp16x2_raw h; unsigned u; } c;
  c.h = __builtin_amdgcn_cvt_pkrtz(a, b);
  return c.u;
}
__device__ __forceinline__ f32x4 mfma16(f16x8 a, f16x8 b, f32x4 c) {
  return __builtin_amdgcn_mfma_f32_16x16x32_f16(a, b, c, 0, 0, 0);
}
__device__ __forceinline__ float fast_exp2(float x) {
#if __has_builtin(__builtin_amdgcn_exp2f)
  return __builtin_amdgcn_exp2f(x);
#else
  return exp2f(x);
#endif
}

// ---------------- GEMM (fp32 inputs, inline f16 convert) ---------------------
// out[n][o] = (sum_k A[n][k]*W[o][k] + bias[o])*scale.  128(m)x64(n) tile,
// BK=64, 4 waves 2x2 (wave = 64m x 32n).  Staging: reg-staged float4 loads ->
// cvt_pkrtz -> ds_write_b128 at XOR-swizzled unit ((gu ^ (row&7))*8); reads
// use the same XOR -> conflict-reduced (write/read both-sides swizzle).
// Next tile's loads are issued before the 2nd barrier (hidden under MFMA).
// TRANS=1: write f16 transposed per-head: out[h=col>>6][col&63][token].
template <int TRANS>
__device__ __forceinline__ void gemm_body_f32(
    const float* __restrict__ A, const float* __restrict__ W,
    const float* __restrict__ bias, void* __restrict__ out, float oscale) {
  __shared__ __align__(16) unsigned short As[128 * 64];
  __shared__ __align__(16) unsigned short Bs[64 * 64];
  const int t = threadIdx.x;
  const int lane = t & 63, w = t >> 6;
  const int wm = w & 1, wn = w >> 1;
  const int q4 = lane >> 4, i15 = lane & 15;
  const int m0 = blockIdx.y * 128, n0 = blockIdx.x * 64;
  f32x4 acc[4][2] = {};
  // A staging: lane -> row lra = lane>>1 (32 rows/wave), k-half (lane&1)*32
  const int lra = lane >> 1;
  const float* agp = A + (size_t)(m0 + w * 32 + lra) * 512 + (lane & 1) * 32;
  unsigned short* asw = As + (w * 32 + lra) * 64;
  int aidx[4];
#pragma unroll
  for (int u = 0; u < 4; ++u)
    aidx[u] = (((lane & 1) * 4 + u) ^ (lra & 7)) * 8;
  // B staging: lane -> row lrb = lane>>2 (16 rows/wave), k-quarter (lane&3)*16
  const int lrb = lane >> 2;
  const float* bgp = W + (size_t)(n0 + w * 16 + lrb) * 512 + (lane & 3) * 16;
  unsigned short* bsw = Bs + (w * 16 + lrb) * 64;
  int bidx[2];
#pragma unroll
  for (int u = 0; u < 2; ++u)
    bidx[u] = (((lane & 3) * 2 + u) ^ (lrb & 7)) * 8;
  const int h8 = i15 & 7;  // read-side swizzle key
  float4 fa[8], fb[4];
#pragma unroll
  for (int j = 0; j < 8; ++j) fa[j] = *(const float4*)(agp + j * 4);
#pragma unroll
  for (int j = 0; j < 4; ++j) fb[j] = *(const float4*)(bgp + j * 4);
  for (int k0 = 0; k0 < 512; k0 += 64) {
    __syncthreads();
#pragma unroll
    for (int u = 0; u < 4; ++u) {
      uint4 o;
      o.x = pack_f16(fa[2 * u].x, fa[2 * u].y);
      o.y = pack_f16(fa[2 * u].z, fa[2 * u].w);
      o.z = pack_f16(fa[2 * u + 1].x, fa[2 * u + 1].y);
      o.w = pack_f16(fa[2 * u + 1].z, fa[2 * u + 1].w);
      *(uint4*)(asw + aidx[u]) = o;
    }
#pragma unroll
    for (int u = 0; u < 2; ++u) {
      uint4 o;
      o.x = pack_f16(fb[2 * u].x, fb[2 * u].y);
      o.y = pack_f16(fb[2 * u].z, fb[2 * u].w);
      o.z = pack_f16(fb[2 * u + 1].x, fb[2 * u + 1].y);
      o.w = pack_f16(fb[2 * u + 1].z, fb[2 * u + 1].w);
      *(uint4*)(bsw + bidx[u]) = o;
    }
    if (k0 < 448) {  // uniform branch: prefetch next K-tile under MFMA
#pragma unroll
      for (int j = 0; j < 8; ++j)
        fa[j] = *(const float4*)(agp + k0 + 64 + j * 4);
#pragma unroll
      for (int j = 0; j < 4; ++j)
        fb[j] = *(const float4*)(bgp + k0 + 64 + j * 4);
    }
    __syncthreads();
#pragma unroll
    for (int ks = 0; ks < 2; ++ks) {
      f16x8 af[4], bfr[2];
#pragma unroll
      for (int mt = 0; mt < 4; ++mt)
        af[mt] = *(const f16x8*)(As + (wm * 64 + mt * 16 + i15) * 64 +
                                 (((ks * 4 + q4) ^ h8) * 8));
#pragma unroll
      for (int nt = 0; nt < 2; ++nt)
        bfr[nt] = *(const f16x8*)(Bs + (wn * 32 + nt * 16 + i15) * 64 +
                                  (((ks * 4 + q4) ^ h8) * 8));
#pragma unroll
      for (int mt = 0; mt < 4; ++mt)
#pragma unroll
        for (int nt = 0; nt < 2; ++nt)
          acc[mt][nt] = mfma16(af[mt], bfr[nt], acc[mt][nt]);
    }
  }
  // epilogue: C layout col = lane&15 (+16nt+32wn), row = quad*4+reg (+16mt+64wm)
#pragma unroll
  for (int nt = 0; nt < 2; ++nt) {
    int col = n0 + wn * 32 + nt * 16 + i15;
    float bv = bias[col];
    if (TRANS) {
      unsigned short* ob_ = (unsigned short*)out +
                            (size_t)(col >> 6) * (64 * N_TOK) +
                            (size_t)(col & 63) * N_TOK;
#pragma unroll
      for (int mt = 0; mt < 4; ++mt) {
        int rowb = m0 + wm * 64 + mt * 16 + q4 * 4;
        uint2 pr;
        pr.x = pack_f16(acc[mt][nt][0] + bv, acc[mt][nt][1] + bv);
        pr.y = pack_f16(acc[mt][nt][2] + bv, acc[mt][nt][3] + bv);
        *(uint2*)(ob_ + rowb) = pr;
      }
    } else {
#pragma unroll
      for (int mt = 0; mt < 4; ++mt) {
        int rowb = m0 + wm * 64 + mt * 16 + q4 * 4;
#pragma unroll
        for (int rr = 0; rr < 4; ++rr) {
          int idx = (rowb + rr) * 512 + col;
          float val = (acc[mt][nt][rr] + bv) * oscale;
          ((unsigned short*)out)[idx] = f2h(val);
        }
      }
    }
  }
}

// ---------------- qkv GEMMs + mask bitpack in one launch ---------------------
// grid (8,32,7): z<3 = Q/K/V GEMM slices; z in [3,7) = 1024 mask blocks, each
// packs 16 wave-units/wave (mask proven int32 {0,1} by earlier rounds) into
// TRANSPOSED u64 bitsT[64 words][4096 rows]. The 64MB mask read streams
// concurrently with the latency-bound GEMM blocks.
__global__ __launch_bounds__(256) void qkv_mask_kernel(
    const float* __restrict__ q, const float* __restrict__ k,
    const float* __restrict__ v, const float* __restrict__ wq,
    const float* __restrict__ wk, const float* __restrict__ wv,
    const float* __restrict__ bq, const float* __restrict__ bk,
    const float* __restrict__ bv, const int* __restrict__ m,
    unsigned long long* __restrict__ bitsT,
    unsigned short* __restrict__ outbase) {
  int z = blockIdx.z;
  if (z == 0) {
    gemm_body_f32<0>(q, wq, bq, outbase, QSCALE);
  } else if (z == 1) {
    gemm_body_f32<0>(k, wk, bk, outbase + (size_t)N_TOK * 512, 1.0f);
  } else if (z == 2) {
    gemm_body_f32<1>(v, wv, bv, outbase + 2ull * N_TOK * 512, 1.0f);
  } else {
    int sb = (z - 3) * 256 + blockIdx.y * 8 + blockIdx.x;  // 0..1023
    int wid = threadIdx.x >> 6, lane = threadIdx.x & 63;
#pragma unroll 2
    for (int it = 0; it < 16; ++it) {
      int wvi = sb * 64 + it * 4 + wid;  // 0..65535
      int row = wvi >> 4;                // mask row
      int sub = wvi & 15;                // 256-elem j-slice within the row
      int base = wvi * 256;
      unsigned long long b0 = __ballot(m[base + 0 * 64 + lane] != 0);
      unsigned long long b1 = __ballot(m[base + 1 * 64 + lane] != 0);
      unsigned long long b2 = __ballot(m[base + 2 * 64 + lane] != 0);
      unsigned long long b3 = __ballot(m[base + 3 * 64 + lane] != 0);
      if (lane < 4) {
        unsigned long long bl =
            lane == 0 ? b0 : lane == 1 ? b1 : lane == 2 ? b2 : b3;
        bitsT[(size_t)(sub * 4 + lane) * N_TOK + row] = bl;
      }
    }
  }
}

// ---------------- output GEMM: fused split-KV reduce + inline W convert ------
// A[row][k] = (sum_c Op[c][h][row][d]) / den[h][row], h=k>>6, d=k&63, built
// on the fly into the XOR-swizzled f16 LDS image (reg-staged ds_write);
// B staged from fp32 W with the same inline cvt_pkrtz path.
// inv_den[128 rows][8 heads] precomputed in prologue LDS.
__global__ __launch_bounds__(256) void out_gemm_kernel(
    const float* __restrict__ Op, const float* __restrict__ dp,
    const float* __restrict__ W, const float* __restrict__ bias,
    float* __restrict__ out) {
  __shared__ __align__(16) unsigned short As[128 * 64];
  __shared__ __align__(16) unsigned short Bs[64 * 64];
  __shared__ float inv_lds[128 * 8];
  const int t = threadIdx.x;
  const int lane = t & 63, w = t >> 6;
  const int wm = w & 1, wn = w >> 1;
  const int q4 = lane >> 4, i15 = lane & 15;
  const int m0 = blockIdx.y * 128, n0 = blockIdx.x * 64;
  const size_t CH = (size_t)8 * N_TOK * 64;  // floats per Op chunk
  f32x4 acc[4][2] = {};
  // prologue: inv_den table (idx = r*8 + h)
#pragma unroll
  for (int ii = 0; ii < 4; ++ii) {
    int idx = t * 4 + ii;
    int r = idx >> 3, h = idx & 7;
    float dden = dp[(size_t)h * N_TOK + m0 + r];
    dden += dp[(size_t)(8 + h) * N_TOK + m0 + r];
    dden += dp[(size_t)(16 + h) * N_TOK + m0 + r];
    dden += dp[(size_t)(24 + h) * N_TOK + m0 + r];
    inv_lds[idx] = 1.0f / dden;
  }
  const int lr = lane >> 3;
  const int u8 = lane & 7;
  const int lrb = lane >> 2;
  const float* bgp = W + (size_t)(n0 + w * 16 + lrb) * 512 + (lane & 3) * 16;
  unsigned short* bsw = Bs + (w * 16 + lrb) * 64;
  int bidx[2];
#pragma unroll
  for (int u = 0; u < 2; ++u)
    bidx[u] = (((lane & 3) * 2 + u) ^ (lrb & 7)) * 8;
  const int h8 = i15 & 7;
  for (int k0 = 0; k0 < 512; k0 += 64) {
    int h = k0 >> 6;
    __syncthreads();
    // B loads issued first (fp32), hidden under the A reduce phase
    float4 fb[4];
#pragma unroll
    for (int j = 0; j < 4; ++j) fb[j] = *(const float4*)(bgp + k0 + j * 4);
    // A: reg-staged reduce -> f16 -> swizzled ds_write
#pragma unroll
    for (int i = 0; i < 4; ++i) {
      int row = w * 32 + i * 8 + lr;
      size_t base = ((size_t)h * N_TOK + m0 + row) * 64 + u8 * 8;
      float4 a0 = *(const float4*)(Op + base);
      float4 a0b = *(const float4*)(Op + base + 4);
      float4 a1 = *(const float4*)(Op + CH + base);
      float4 a1b = *(const float4*)(Op + CH + base + 4);
      float4 a2 = *(const float4*)(Op + 2 * CH + base);
      float4 a2b = *(const float4*)(Op + 2 * CH + base + 4);
      float4 a3 = *(const float4*)(Op + 3 * CH + base);
      float4 a3b = *(const float4*)(Op + 3 * CH + base + 4);
      float inv = inv_lds[row * 8 + h];
      float s0 = ((a0.x + a1.x) + a2.x) + a3.x;
      float s1 = ((a0.y + a1.y) + a2.y) + a3.y;
      float s2 = ((a0.z + a1.z) + a2.z) + a3.z;
      float s3 = ((a0.w + a1.w) + a2.w) + a3.w;
      float s4 = ((a0b.x + a1b.x) + a2b.x) + a3b.x;
      float s5 = ((a0b.y + a1b.y) + a2b.y) + a3b.y;
      float s6 = ((a0b.z + a1b.z) + a2b.z) + a3b.z;
      float s7 = ((a0b.w + a1b.w) + a2b.w) + a3b.w;
      uint4 o;
      o.x = pack_f16(s0 * inv, s1 * inv);
      o.y = pack_f16(s2 * inv, s3 * inv);
      o.z = pack_f16(s4 * inv, s5 * inv);
      o.w = pack_f16(s6 * inv, s7 * inv);
      *(uint4*)(As + row * 64 + ((u8 ^ lr) * 8)) = o;
    }
    // B: cvt -> swizzled ds_write (loads have returned by now)
#pragma unroll
    for (int u = 0; u < 2; ++u) {
      uint4 o;
      o.x = pack_f16(fb[2 * u].x, fb[2 * u].y);
      o.y = pack_f16(fb[2 * u].z, fb[2 * u].w);
      o.z = pack_f16(fb[2 * u + 1].x, fb[2 * u + 1].y);
      o.w = pack_f16(fb[2 * u + 1].z, fb[2 * u + 1].w);
      *(uint4*)(bsw + bidx[u]) = o;
    }
    __syncthreads();
#pragma unroll
    for (int ks = 0; ks < 2; ++ks) {
      f16x8 af[4], bfr[2];
#pragma unroll
      for (int mt = 0; mt < 4; ++mt)
        af[mt] = *(const f16x8*)(As + (wm * 64 + mt * 16 + i15) * 64 +
                                 (((ks * 4 + q4) ^ h8) * 8));
#pragma unroll
      for (int nt = 0; nt < 2; ++nt)
        bfr[nt] = *(const f16x8*)(Bs + (wn * 32 + nt * 16 + i15) * 64 +
                                  (((ks * 4 + q4) ^ h8) * 8));
#pragma unroll
      for (int mt = 0; mt < 4; ++mt)
#pragma unroll
        for (int nt = 0; nt < 2; ++nt)
          acc[mt][nt] = mfma16(af[mt], bfr[nt], acc[mt][nt]);
    }
  }
  // epilogue: fp32 out
#pragma unroll
  for (int nt = 0; nt < 2; ++nt) {
    int col = n0 + wn * 32 + nt * 16 + i15;
    float bv = bias[col];
#pragma unroll
    for (int mt = 0; mt < 4; ++mt) {
      int rowb = m0 + wm * 64 + mt * 16 + q4 * 4;
#pragma unroll
      for (int rr = 0; rr < 4; ++rr)
        out[(rowb + rr) * 512 + col] = acc[mt][nt][rr] + bv;
    }
  }
}

// ---------------- split-KV flash attention -----------------------------------
// Block: 256 threads = 4 waves; 128 q-rows x head x 1024-j chunk (4 blocks/CU).
// Per 64-j tile: K/V staged cooperatively into double-buffered LDS, ONE
// barrier/tile. All LDS addresses precomputed per-lane (loop unrolled x2 so
// the buffer base is a compile-time offset immediate); global K/V/mask are
// running pointers. S^T = K*Q^T, p = exp2 (mask select-to--200), pack via
// v_cvt_pkrtz directly into [nt][ks] unions (PV B-frag = those regs, no
// repack), s_setprio(1) around MFMA clusters (T5), O^T += V^T*P^T.
#define ATTN_BODY(BUF, MWIN, MWOUT)                                           \
  do {                                                                        \
    char* KsB = (char*)(Ks[BUF]);                                             \
    char* VtB = (char*)(Vt[BUF]);                                             \
    *(uint4*)(KsB + ksto0) = kst0;                                            \
    *(uint4*)(KsB + ksto1) = kst1;                                            \
    {                                                                         \
      const unsigned* vs = (const unsigned*)&vst0;                            \
      *(uint2*)(VtB + vsto00) = make_uint2(vs[0], vs[1]);                     \
      *(uint2*)(VtB + vsto01) = make_uint2(vs[2], vs[3]);                     \
    }                                                                         \
    {                                                                         \
      const unsigned* vs = (const unsigned*)&vst1;                            \
      *(uint2*)(VtB + vsto10) = make_uint2(vs[0], vs[1]);                     \
      *(uint2*)(VtB + vsto11) = make_uint2(vs[2], vs[3]);                     \
    }                                                                         \
    __syncthreads();                                                          \
    kst0 = *(const uint4*)(kgp);                                              \
    kst1 = *(const uint4*)(kgp + 8192);                                       \
    vst0 = *(const uint4*)(vgp);                                              \
    vst1 = *(const uint4*)(vgp + 65536);                                      \
    MWOUT[0] = *(const unsigned long long*)(mgp);                             \
    MWOUT[1] = *(const unsigned long long*)(mgp + 128);                       \
    kgp += 65536;                                                             \
    vgp += 128;                                                               \
    mgp += 32768;                                                             \
    unsigned long long mq0 = MWIN[0] >> (q4 * 4);                             \
    unsigned long long mq1 = MWIN[1] >> (q4 * 4);                             \
    pku_t pk[2][2];                                                           \
    _Pragma("unroll") for (int mtj = 0; mtj < 4; ++mtj) {                     \
      f16x8 Kf0 = *(const f16x8*)(KsB + kfo[mtj][0]);                         \
      f16x8 Kf1 = *(const f16x8*)(KsB + kfo[mtj][1]);                         \
      _Pragma("unroll") for (int nt = 0; nt < 2; ++nt) {                      \
        f32x4 s = {0.f, 0.f, 0.f, 0.f};                                       \
        __builtin_amdgcn_s_setprio(1);                                        \
        s = mfma16(Kf0, qf[nt][0], s);                                        \
        s = mfma16(Kf1, qf[nt][1], s);                                        \
        __builtin_amdgcn_s_setprio(0);                                        \
        unsigned nib =                                                        \
            (unsigned)((nt ? mq1 : mq0) >> (mtj * 16)) & 15u;                 \
        float p0 = fast_exp2((nib & 1u) ? -200.f : s[0]);                     \
        float p1 = fast_exp2((nib & 2u) ? -200.f : s[1]);                     \
        float p2 = fast_exp2((nib & 4u) ? -200.f : s[2]);                     \
        float p3 = fast_exp2((nib & 8u) ? -200.f : s[3]);                     \
        den[nt] += (p0 + p1) + (p2 + p3);                                     \
        pk[nt][mtj >> 1].u[(mtj & 1) * 2] = pack_f16(p0, p1);                 \
        pk[nt][mtj >> 1].u[(mtj & 1) * 2 + 1] = pack_f16(p2, p3);             \
      }                                                                       \
    }                                                                         \
    __builtin_amdgcn_s_setprio(1);                                            \
    _Pragma("unroll") for (int ks = 0; ks < 2; ++ks) {                        \
      f16x8 Vf[4];                                                            \
      _Pragma("unroll") for (int mtd = 0; mtd < 4; ++mtd) Vf[mtd] =           \
          *(const f16x8*)(VtB + vfo[ks][mtd]);                                \
      _Pragma("unroll") for (int nt = 0; nt < 2; ++nt) {                      \
        _Pragma("unroll") for (int mtd = 0; mtd < 4; ++mtd) oacc[mtd][nt] =   \
            mfma16(Vf[mtd], pk[nt][ks].v, oacc[mtd][nt]);                     \
      }                                                                       \
    }                                                                         \
    __builtin_amdgcn_s_setprio(0);                                            \
  } while (0)

__global__ __launch_bounds__(256, 2) void attn_kernel(
    const unsigned short* __restrict__ qp, const unsigned short* __restrict__ kp,
    const unsigned short* __restrict__ vpT,
    const unsigned long long* __restrict__ mbT,
    float* __restrict__ Op, float* __restrict__ dp) {
  __shared__ unsigned short Ks[2][64 * 64];
  __shared__ unsigned short Vt[2][64 * 64];
  const int t = threadIdx.x;
  const int l = t & 63, w = t >> 6;
  const int q4 = l >> 4, i15 = l & 15;
  const int iblk = blockIdx.x * 128;
  const int head = blockIdx.y;
  const int chunk = blockIdx.z;
  const int ch = head * 64;
  const int i0 = iblk + w * 32;
  const int ji = l >> 3;
  const int sg = l & 7;
  const int r0 = w * 2;
  const int j0base = chunk * 1024;
  // Q B-fragments in registers for the whole kernel
  f16x8 qf[2][2];
#pragma unroll
  for (int nt = 0; nt < 2; ++nt) {
    const unsigned short* qr = qp + (size_t)(i0 + nt * 16 + i15) * 512 + ch;
#pragma unroll
    for (int ks = 0; ks < 2; ++ks)
      qf[nt][ks] = *(const f16x8*)(qr + ks * 32 + q4 * 8);
  }
  f32x4 oacc[4][2] = {};
  float den[2] = {0.f, 0.f};
  // ---- precomputed lane-constant LDS byte offsets
  int kfo[4][2], vfo[2][4];
#pragma unroll
  for (int mtj = 0; mtj < 4; ++mtj) {
    int js = mtj * 16 + i15;
    int h = (js & 7) ^ (js >> 3);
#pragma unroll
    for (int ksd = 0; ksd < 2; ++ksd)
      kfo[mtj][ksd] = (js * 64 + (((ksd * 4 + q4) ^ h) * 8)) * 2;
  }
#pragma unroll
  for (int ks = 0; ks < 2; ++ks)
#pragma unroll
    for (int mtd = 0; mtd < 4; ++mtd) {
      int d = mtd * 16 + i15;
      int h = (d & 7) ^ (d >> 3);
      vfo[ks][mtd] = (d * 64 + (((ks * 4 + q4) ^ h) * 8)) * 2;
    }
  int ksto0, ksto1, vsto00, vsto01, vsto10, vsto11;
  {
    int r = r0, row = r * 8 + ji;
    ksto0 = (row * 64 + ((sg ^ ji ^ r) * 8)) * 2;
    int hh = (sg >> 1) & 1;
    int kg0 = (sg >> 2) * 4 + (sg & 1) * 2;
    vsto00 = (row * 64 + ((kg0 ^ ji ^ r) * 8) + hh * 4) * 2;
    vsto01 = (row * 64 + (((kg0 + 1) ^ ji ^ r) * 8) + hh * 4) * 2;
    r = r0 + 1; row = r * 8 + ji;
    ksto1 = (row * 64 + ((sg ^ ji ^ r) * 8)) * 2;
    vsto10 = (row * 64 + ((kg0 ^ ji ^ r) * 8) + hh * 4) * 2;
    vsto11 = (row * 64 + (((kg0 + 1) ^ ji ^ r) * 8) + hh * 4) * 2;
  }
  // ---- running global pointers (advance by constant stride per tile)
  const char* kgp =
      (const char*)kp + ((size_t)(j0base + r0 * 8 + ji) * 512 + ch + sg * 8) * 2;
  const char* vgp = (const char*)(vpT + (size_t)head * 64 * N_TOK) +
                    ((size_t)(r0 * 8 + ji) * N_TOK + j0base + sg * 8) * 2;
  const char* mgp =
      (const char*)mbT + ((size_t)(chunk * 16) * N_TOK + i0 + i15) * 8;
  uint4 kst0, kst1, vst0, vst1;
  unsigned long long mwc[2], mwn[2];
  // prefetch tile 0 (+ its mask words)
  kst0 = *(const uint4*)(kgp);
  kst1 = *(const uint4*)(kgp + 8192);
  vst0 = *(const uint4*)(vgp);
  vst1 = *(const uint4*)(vgp + 65536);
  mwc[0] = *(const unsigned long long*)(mgp);
  mwc[1] = *(const unsigned long long*)(mgp + 128);
  kgp += 65536;
  vgp += 128;
  mgp += 32768;
  // 16 tiles, unrolled x2 (double-buffer base = compile-time offset).
  // Final bodies prefetch past the chunk end -- lands in adjacent mapped
  // workspace regions, loaded into regs but never consumed.
  for (int jp = 0; jp < 8; ++jp) {
    ATTN_BODY(0, mwc, mwn);
    ATTN_BODY(1, mwn, mwc);
  }
  // ---- write fp32 partials: Op[chunk][head][i][64], dp[chunk][head][i]
  float* Opc = Op + ((size_t)(chunk * 8 + head) * N_TOK) * 64;
#pragma unroll
  for (int nt = 0; nt < 2; ++nt) {
    float dn = den[nt];
    dn += __shfl_xor(dn, 16);
    dn += __shfl_xor(dn, 32);
    int row = i0 + nt * 16 + i15;
#pragma unroll
    for (int mtd = 0; mtd < 4; ++mtd)
      *(f32x4*)(Opc + (size_t)row * 64 + mtd * 16 + q4 * 4) = oacc[mtd][nt];
    if (q4 == 0) dp[(size_t)(chunk * 8 + head) * N_TOK + row] = dn;
  }
}

// ---------------- launch -----------------------------------------------------
extern "C" void kernel_launch(void* const* d_in, const int* in_sizes, int n_in,
                              void* d_out, int out_size, void* d_ws, size_t ws_size,
                              hipStream_t stream) {
  const float* q = (const float*)d_in[0];
  const float* k = (const float*)d_in[1];
  const float* v = (const float*)d_in[2];
  const int* mask = (const int*)d_in[3];
  const float* wq = (const float*)d_in[4];
  const float* bq = (const float*)d_in[5];
  const float* wk = (const float*)d_in[6];
  const float* bk = (const float*)d_in[7];
  const float* wv = (const float*)d_in[8];
  const float* bv = (const float*)d_in[9];
  const float* wo = (const float*)d_in[10];
  const float* bo = (const float*)d_in[11];

  char* ws = (char*)d_ws;
  const size_t MB = 1ull << 20;
  unsigned long long* mbT = (unsigned long long*)(ws + 1 * MB);  // 2 MiB
  unsigned short* qkvp = (unsigned short*)(ws + 3 * MB);  // 12 MiB: qp,kp,vpT
  float* Op = (float*)(ws + 19 * MB);                     // 32 MiB
  float* dp = (float*)(ws + 51 * MB);                     // 512 KiB

  qkv_mask_kernel<<<dim3(8, 32, 7), 256, 0, stream>>>(
      q, k, v, wq, wk, wv, bq, bk, bv, mask, mbT, qkvp);
  attn_kernel<<<dim3(32, 8, 4), 256, 0, stream>>>(
      qkvp, qkvp + (size_t)N_TOK * 512, qkvp + 2ull * N_TOK * 512, mbT, Op, dp);
  out_gemm_kernel<<<dim3(8, 32), 256, 0, stream>>>(Op, dp, wo, bo,
                                                   (float*)d_out);
}

// Round 8
// 248.297 us; speedup vs baseline: 1.0747x; 1.0747x over previous
//
#include <hip/hip_runtime.h>

// MultiheadAttention N=4096, d_model=512, 8 heads, d_head=64.
// fp32 inputs/output, f16 MFMA pipeline. 4-kernel pipeline (round-4-verified
// components; round-6's fp32-direct GEMM reverted -- it overfetched 133MB):
//  prep: mask bitpack (uint4 loads + nibble-LDS repack) + fp32->f16 converts ;
//  qkv GEMM: f16 inputs, global_load_lds(16B) staging, pre-swizzled source ;
//  attn: split-KV flash attention (verified, unchanged) ;
//  out_gemm: fused split-KV reduce on A-side (reg-staged swizzled ds_write),
//  f16 W via gload_lds on B-side.

typedef __attribute__((ext_vector_type(8))) _Float16 f16x8;
typedef __attribute__((ext_vector_type(2))) __fp16 fp16x2_raw;  // cvt_pkrtz ret
typedef __attribute__((ext_vector_type(4))) float f32x4;

union pku_t { unsigned u[4]; f16x8 v; };

#define N_TOK 4096
#define QSCALE 0.18033688f  // 0.125 * log2(e)

__device__ __forceinline__ unsigned short f2h(float f) {
  union { _Float16 h; unsigned short u; } c;
  c.h = (_Float16)f;
  return c.u;
}
// packed f32x2 -> f16x2 in ONE instruction (v_cvt_pkrtz_f16_f32).
__device__ __forceinline__ unsigned pack_f16(float a, float b) {
  union { fp16x2_raw h; unsigned u; } c;
  c.h = __builtin_amdgcn_cvt_pkrtz(a, b);
  return c.u;
}
__device__ __forceinline__ f32x4 mfma16(f16x8 a, f16x8 b, f32x4 c) {
  return __builtin_amdgcn_mfma_f32_16x16x32_f16(a, b, c, 0, 0, 0);
}
__device__ __forceinline__ float fast_exp2(float x) {
#if __has_builtin(__builtin_amdgcn_exp2f)
  return __builtin_amdgcn_exp2f(x);
#else
  return exp2f(x);
#endif
}
// async global->LDS, 16B per lane; LDS dest is wave-uniform base + lane*16.
__device__ __forceinline__ void gload_lds16(const void* g, void* l) {
  __builtin_amdgcn_global_load_lds(
      (const __attribute__((address_space(1))) void*)g,
      (__attribute__((address_space(3))) void*)l, 16, 0, 0);
}

// ---------------- prep: mask bit-pack + fp32->f16 converts (one launch) ------
// blocks [0,16384): mask -> TRANSPOSED u64 bitsT[64 words][4096 rows].
//   uint4 load (4 int32 mask elems {0,1} per lane, 16B/lane) -> 4-bit nibble
//   -> LDS byte -> lanes 0..3/wave assemble u64 words via shift-pack.
// blocks [16384,19968): bulk convert of q,k,v (1024 blocks each) and
//   wq,wk,wv,wo (128 blocks each), 8 floats/thread.
__global__ __launch_bounds__(256) void prep_kernel(
    const int* __restrict__ m, unsigned long long* __restrict__ bitsT,
    const float* __restrict__ s0, const float* __restrict__ s1,
    const float* __restrict__ s2, const float* __restrict__ s3,
    const float* __restrict__ s4, const float* __restrict__ s5,
    const float* __restrict__ s6, unsigned short* __restrict__ d0,
    unsigned short* __restrict__ d1, unsigned short* __restrict__ d2,
    unsigned short* __restrict__ d3, unsigned short* __restrict__ d4,
    unsigned short* __restrict__ d5, unsigned short* __restrict__ d6) {
  __shared__ __align__(16) unsigned char nl[256];
  int bx = blockIdx.x;
  int t = threadIdx.x;
  if (bx < 16384) {
    // each block covers 1024 mask elems starting at bx*1024
    uint4 x = *(const uint4*)(m + (size_t)bx * 1024 + t * 4);
    unsigned nib = (x.x != 0 ? 1u : 0u) | (x.y != 0 ? 2u : 0u) |
                   (x.z != 0 ? 4u : 0u) | (x.w != 0 ? 8u : 0u);
    nl[t] = (unsigned char)nib;
    __syncthreads();
    int j = t & 63;
    if (j < 4) {
      int w = t >> 6;
      uint4 nb = *(const uint4*)(nl + w * 64 + j * 16);
      const unsigned* nd = (const unsigned*)&nb;
      unsigned long long word = 0;
#pragma unroll
      for (int d = 0; d < 4; ++d) {
        unsigned y = (nd[d] | (nd[d] >> 4)) & 0x00FF00FFu;
        y = (y | (y >> 8)) & 0x0000FFFFu;
        word |= (unsigned long long)y << (16 * d);
      }
      int eb = bx * 1024 + w * 256 + j * 64;  // first elem of this word
      int row = eb >> 12;                     // mask row
      int jw = (eb & 4095) >> 6;              // word index within row
      bitsT[(size_t)jw * N_TOK + row] = word;
    }
    return;
  }
  int b2i = bx - 16384;
  int z, blk;
  if (b2i < 3072) { z = b2i >> 10; blk = b2i & 1023; }
  else { int wb = b2i - 3072; z = 3 + (wb >> 7); blk = wb & 127; }
  const float* src = z == 0 ? s0 : z == 1 ? s1 : z == 2 ? s2 : z == 3 ? s3
                     : z == 4 ? s4 : z == 5 ? s5 : s6;
  unsigned short* dst = z == 0 ? d0 : z == 1 ? d1 : z == 2 ? d2 : z == 3 ? d3
                        : z == 4 ? d4 : z == 5 ? d5 : d6;
  int idx = (blk * 256 + t) * 8;
  float4 f0 = *(const float4*)(src + idx);
  float4 f1 = *(const float4*)(src + idx + 4);
  uint4 o;
  o.x = pack_f16(f0.x, f0.y);
  o.y = pack_f16(f0.z, f0.w);
  o.z = pack_f16(f1.x, f1.y);
  o.w = pack_f16(f1.z, f1.w);
  *(uint4*)(dst + idx) = o;
}

// ---------------- GEMM: out[n][o] = (sum_k A[n][k]*W[o][k] + bias[o])*scale --
// A,W f16 K-major. 128(m)x64(n) tile, BK=64, 4 waves 2x2 (wave = 64m x 32n).
// Staging: global_load_lds 16B/lane, linear LDS [rows][64] shorts; the 16B
// unit column is XOR-swizzled by (row&7) on the GLOBAL source so ds_reads
// (same XOR) are conflict-reduced (both-sides swizzle, m97/m173 pattern).
// TRANS=1: write f16 transposed per-head: out[h=col>>6][col&63][token].
template <int TRANS>
__device__ __forceinline__ void gemm_body64(
    const unsigned short* __restrict__ A, const unsigned short* __restrict__ W,
    const float* __restrict__ bias, void* __restrict__ out, float oscale) {
  __shared__ __align__(16) unsigned short As[128 * 64];
  __shared__ __align__(16) unsigned short Bs[64 * 64];
  const int t = threadIdx.x;
  const int lane = t & 63, w = t >> 6;
  const int wm = w & 1, wn = w >> 1;
  const int q4 = lane >> 4, i15 = lane & 15;
  const int m0 = blockIdx.y * 128, n0 = blockIdx.x * 64;
  f32x4 acc[4][2] = {};
  const int lr = lane >> 3;
  const int su = (lane & 7) ^ lr;
  const unsigned short* agp = A + (size_t)(m0 + w * 32 + lr) * 512 + su * 8;
  const unsigned short* bgp = W + (size_t)(n0 + w * 16 + lr) * 512 + su * 8;
  unsigned short* asb = As + (w * 32) * 64;
  unsigned short* bsb = Bs + (w * 16) * 64;
  const int h8 = i15 & 7;  // read-side swizzle key
  for (int k0 = 0; k0 < 512; k0 += 64) {
    __syncthreads();
#pragma unroll
    for (int i = 0; i < 4; ++i)
      gload_lds16(agp + i * 8 * 512 + k0, asb + i * 8 * 64);
#pragma unroll
    for (int i = 0; i < 2; ++i)
      gload_lds16(bgp + i * 8 * 512 + k0, bsb + i * 8 * 64);
    __syncthreads();
#pragma unroll
    for (int ks = 0; ks < 2; ++ks) {
      f16x8 af[4], bfr[2];
#pragma unroll
      for (int mt = 0; mt < 4; ++mt)
        af[mt] = *(const f16x8*)(As + (wm * 64 + mt * 16 + i15) * 64 +
                                 (((ks * 4 + q4) ^ h8) * 8));
#pragma unroll
      for (int nt = 0; nt < 2; ++nt)
        bfr[nt] = *(const f16x8*)(Bs + (wn * 32 + nt * 16 + i15) * 64 +
                                  (((ks * 4 + q4) ^ h8) * 8));
#pragma unroll
      for (int mt = 0; mt < 4; ++mt)
#pragma unroll
        for (int nt = 0; nt < 2; ++nt)
          acc[mt][nt] = mfma16(af[mt], bfr[nt], acc[mt][nt]);
    }
  }
  // epilogue: C layout col = lane&15 (+16nt+32wn), row = quad*4+reg (+16mt+64wm)
#pragma unroll
  for (int nt = 0; nt < 2; ++nt) {
    int col = n0 + wn * 32 + nt * 16 + i15;
    float bv = bias[col];
    if (TRANS) {
      unsigned short* ob_ = (unsigned short*)out +
                            (size_t)(col >> 6) * (64 * N_TOK) +
                            (size_t)(col & 63) * N_TOK;
#pragma unroll
      for (int mt = 0; mt < 4; ++mt) {
        int rowb = m0 + wm * 64 + mt * 16 + q4 * 4;
        uint2 pr;
        pr.x = pack_f16(acc[mt][nt][0] + bv, acc[mt][nt][1] + bv);
        pr.y = pack_f16(acc[mt][nt][2] + bv, acc[mt][nt][3] + bv);
        *(uint2*)(ob_ + rowb) = pr;
      }
    } else {
#pragma unroll
      for (int mt = 0; mt < 4; ++mt) {
        int rowb = m0 + wm * 64 + mt * 16 + q4 * 4;
#pragma unroll
        for (int rr = 0; rr < 4; ++rr) {
          int idx = (rowb + rr) * 512 + col;
          float val = (acc[mt][nt][rr] + bv) * oscale;
          ((unsigned short*)out)[idx] = f2h(val);
        }
      }
    }
  }
}

__global__ __launch_bounds__(256) void qkv_gemm_kernel(
    const unsigned short* __restrict__ qc, const unsigned short* __restrict__ kc,
    const unsigned short* __restrict__ vc, const unsigned short* __restrict__ wqc,
    const unsigned short* __restrict__ wkc, const unsigned short* __restrict__ wvc,
    const float* __restrict__ bq, const float* __restrict__ bk,
    const float* __restrict__ bv, unsigned short* __restrict__ outbase) {
  int z = blockIdx.z;
  if (z == 0) {
    gemm_body64<0>(qc, wqc, bq, outbase, QSCALE);
  } else if (z == 1) {
    gemm_body64<0>(kc, wkc, bk, outbase + (size_t)N_TOK * 512, 1.0f);
  } else {
    gemm_body64<1>(vc, wvc, bv, outbase + 2ull * N_TOK * 512, 1.0f);
  }
}

// ---------------- output GEMM with FUSED split-KV reduce ---------------------
// A[row][k] = (sum_c Op[c][h][row][d]) / den[h][row], h=k>>6, d=k&63, built
// on the fly into the same XOR-swizzled f16 LDS image the MFMA loop reads
// (reg-staged ds_write on A side; B side keeps gload_lds from f16 woc).
// inv_den[128 rows][8 heads] precomputed in prologue LDS.
__global__ __launch_bounds__(256) void out_gemm_kernel(
    const float* __restrict__ Op, const float* __restrict__ dp,
    const unsigned short* __restrict__ W, const float* __restrict__ bias,
    float* __restrict__ out) {
  __shared__ __align__(16) unsigned short As[128 * 64];
  __shared__ __align__(16) unsigned short Bs[64 * 64];
  __shared__ float inv_lds[128 * 8];
  const int t = threadIdx.x;
  const int lane = t & 63, w = t >> 6;
  const int wm = w & 1, wn = w >> 1;
  const int q4 = lane >> 4, i15 = lane & 15;
  const int m0 = blockIdx.y * 128, n0 = blockIdx.x * 64;
  const size_t CH = (size_t)8 * N_TOK * 64;  // floats per Op chunk
  f32x4 acc[4][2] = {};
  // prologue: inv_den table (idx = r*8 + h)
#pragma unroll
  for (int ii = 0; ii < 4; ++ii) {
    int idx = t * 4 + ii;
    int r = idx >> 3, h = idx & 7;
    float dden = dp[(size_t)h * N_TOK + m0 + r];
    dden += dp[(size_t)(8 + h) * N_TOK + m0 + r];
    dden += dp[(size_t)(16 + h) * N_TOK + m0 + r];
    dden += dp[(size_t)(24 + h) * N_TOK + m0 + r];
    inv_lds[idx] = 1.0f / dden;
  }
  const int lr = lane >> 3;
  const int u8 = lane & 7;
  const int su = u8 ^ lr;
  const unsigned short* bgp = W + (size_t)(n0 + w * 16 + lr) * 512 + su * 8;
  unsigned short* bsb = Bs + (w * 16) * 64;
  const int h8 = i15 & 7;
  for (int k0 = 0; k0 < 512; k0 += 64) {
    int h = k0 >> 6;
    __syncthreads();
    // B: async gload (pre-swizzled source, linear LDS)
#pragma unroll
    for (int i = 0; i < 2; ++i)
      gload_lds16(bgp + i * 8 * 512 + k0, bsb + i * 8 * 64);
    // A: reg-staged reduce -> f16 -> swizzled ds_write
#pragma unroll
    for (int i = 0; i < 4; ++i) {
      int row = w * 32 + i * 8 + lr;
      size_t base = ((size_t)h * N_TOK + m0 + row) * 64 + u8 * 8;
      float4 a0 = *(const float4*)(Op + base);
      float4 a0b = *(const float4*)(Op + base + 4);
      float4 a1 = *(const float4*)(Op + CH + base);
      float4 a1b = *(const float4*)(Op + CH + base + 4);
      float4 a2 = *(const float4*)(Op + 2 * CH + base);
      float4 a2b = *(const float4*)(Op + 2 * CH + base + 4);
      float4 a3 = *(const float4*)(Op + 3 * CH + base);
      float4 a3b = *(const float4*)(Op + 3 * CH + base + 4);
      float inv = inv_lds[row * 8 + h];
      float s0 = ((a0.x + a1.x) + a2.x) + a3.x;
      float s1 = ((a0.y + a1.y) + a2.y) + a3.y;
      float s2 = ((a0.z + a1.z) + a2.z) + a3.z;
      float s3 = ((a0.w + a1.w) + a2.w) + a3.w;
      float s4 = ((a0b.x + a1b.x) + a2b.x) + a3b.x;
      float s5 = ((a0b.y + a1b.y) + a2b.y) + a3b.y;
      float s6 = ((a0b.z + a1b.z) + a2b.z) + a3b.z;
      float s7 = ((a0b.w + a1b.w) + a2b.w) + a3b.w;
      uint4 o;
      o.x = pack_f16(s0 * inv, s1 * inv);
      o.y = pack_f16(s2 * inv, s3 * inv);
      o.z = pack_f16(s4 * inv, s5 * inv);
      o.w = pack_f16(s6 * inv, s7 * inv);
      *(uint4*)(As + row * 64 + ((u8 ^ lr) * 8)) = o;
    }
    __syncthreads();
#pragma unroll
    for (int ks = 0; ks < 2; ++ks) {
      f16x8 af[4], bfr[2];
#pragma unroll
      for (int mt = 0; mt < 4; ++mt)
        af[mt] = *(const f16x8*)(As + (wm * 64 + mt * 16 + i15) * 64 +
                                 (((ks * 4 + q4) ^ h8) * 8));
#pragma unroll
      for (int nt = 0; nt < 2; ++nt)
        bfr[nt] = *(const f16x8*)(Bs + (wn * 32 + nt * 16 + i15) * 64 +
                                  (((ks * 4 + q4) ^ h8) * 8));
#pragma unroll
      for (int mt = 0; mt < 4; ++mt)
#pragma unroll
        for (int nt = 0; nt < 2; ++nt)
          acc[mt][nt] = mfma16(af[mt], bfr[nt], acc[mt][nt]);
    }
  }
  // epilogue: fp32 out
#pragma unroll
  for (int nt = 0; nt < 2; ++nt) {
    int col = n0 + wn * 32 + nt * 16 + i15;
    float bv = bias[col];
#pragma unroll
    for (int mt = 0; mt < 4; ++mt) {
      int rowb = m0 + wm * 64 + mt * 16 + q4 * 4;
#pragma unroll
      for (int rr = 0; rr < 4; ++rr)
        out[(rowb + rr) * 512 + col] = acc[mt][nt][rr] + bv;
    }
  }
}

// ---------------- split-KV flash attention -----------------------------------
// Block: 256 threads = 4 waves; 128 q-rows x head x 1024-j chunk (4 blocks/CU).
// Per 64-j tile: K/V staged cooperatively into double-buffered LDS, ONE
// barrier/tile. All LDS addresses precomputed per-lane (loop unrolled x2 so
// the buffer base is a compile-time offset immediate); global K/V/mask are
// running pointers. S^T = K*Q^T, p = exp2 (mask select-to--200), pack via
// v_cvt_pkrtz directly into [nt][ks] unions (PV B-frag = those regs, no
// repack), s_setprio(1) around MFMA clusters (T5), O^T += V^T*P^T.
#define ATTN_BODY(BUF, MWIN, MWOUT)                                           \
  do {                                                                        \
    char* KsB = (char*)(Ks[BUF]);                                             \
    char* VtB = (char*)(Vt[BUF]);                                             \
    *(uint4*)(KsB + ksto0) = kst0;                                            \
    *(uint4*)(KsB + ksto1) = kst1;                                            \
    {                                                                         \
      const unsigned* vs = (const unsigned*)&vst0;                            \
      *(uint2*)(VtB + vsto00) = make_uint2(vs[0], vs[1]);                     \
      *(uint2*)(VtB + vsto01) = make_uint2(vs[2], vs[3]);                     \
    }                                                                         \
    {                                                                         \
      const unsigned* vs = (const unsigned*)&vst1;                            \
      *(uint2*)(VtB + vsto10) = make_uint2(vs[0], vs[1]);                     \
      *(uint2*)(VtB + vsto11) = make_uint2(vs[2], vs[3]);                     \
    }                                                                         \
    __syncthreads();                                                          \
    kst0 = *(const uint4*)(kgp);                                              \
    kst1 = *(const uint4*)(kgp + 8192);                                       \
    vst0 = *(const uint4*)(vgp);                                              \
    vst1 = *(const uint4*)(vgp + 65536);                                      \
    MWOUT[0] = *(const unsigned long long*)(mgp);                             \
    MWOUT[1] = *(const unsigned long long*)(mgp + 128);                       \
    kgp += 65536;                                                             \
    vgp += 128;                                                               \
    mgp += 32768;                                                             \
    unsigned long long mq0 = MWIN[0] >> (q4 * 4);                             \
    unsigned long long mq1 = MWIN[1] >> (q4 * 4);                             \
    pku_t pk[2][2];                                                           \
    _Pragma("unroll") for (int mtj = 0; mtj < 4; ++mtj) {                     \
      f16x8 Kf0 = *(const f16x8*)(KsB + kfo[mtj][0]);                         \
      f16x8 Kf1 = *(const f16x8*)(KsB + kfo[mtj][1]);                         \
      _Pragma("unroll") for (int nt = 0; nt < 2; ++nt) {                      \
        f32x4 s = {0.f, 0.f, 0.f, 0.f};                                       \
        __builtin_amdgcn_s_setprio(1);                                        \
        s = mfma16(Kf0, qf[nt][0], s);                                        \
        s = mfma16(Kf1, qf[nt][1], s);                                        \
        __builtin_amdgcn_s_setprio(0);                                        \
        unsigned nib =                                                        \
            (unsigned)((nt ? mq1 : mq0) >> (mtj * 16)) & 15u;                 \
        float p0 = fast_exp2((nib & 1u) ? -200.f : s[0]);                     \
        float p1 = fast_exp2((nib & 2u) ? -200.f : s[1]);                     \
        float p2 = fast_exp2((nib & 4u) ? -200.f : s[2]);                     \
        float p3 = fast_exp2((nib & 8u) ? -200.f : s[3]);                     \
        den[nt] += (p0 + p1) + (p2 + p3);                                     \
        pk[nt][mtj >> 1].u[(mtj & 1) * 2] = pack_f16(p0, p1);                 \
        pk[nt][mtj >> 1].u[(mtj & 1) * 2 + 1] = pack_f16(p2, p3);             \
      }                                                                       \
    }                                                                         \
    __builtin_amdgcn_s_setprio(1);                                            \
    _Pragma("unroll") for (int ks = 0; ks < 2; ++ks) {                        \
      f16x8 Vf[4];                                                            \
      _Pragma("unroll") for (int mtd = 0; mtd < 4; ++mtd) Vf[mtd] =           \
          *(const f16x8*)(VtB + vfo[ks][mtd]);                                \
      _Pragma("unroll") for (int nt = 0; nt < 2; ++nt) {                      \
        _Pragma("unroll") for (int mtd = 0; mtd < 4; ++mtd) oacc[mtd][nt] =   \
            mfma16(Vf[mtd], pk[nt][ks].v, oacc[mtd][nt]);                     \
      }                                                                       \
    }                                                                         \
    __builtin_amdgcn_s_setprio(0);                                            \
  } while (0)

__global__ __launch_bounds__(256, 2) void attn_kernel(
    const unsigned short* __restrict__ qp, const unsigned short* __restrict__ kp,
    const unsigned short* __restrict__ vpT,
    const unsigned long long* __restrict__ mbT,
    float* __restrict__ Op, float* __restrict__ dp) {
  __shared__ unsigned short Ks[2][64 * 64];
  __shared__ unsigned short Vt[2][64 * 64];
  const int t = threadIdx.x;
  const int l = t & 63, w = t >> 6;
  const int q4 = l >> 4, i15 = l & 15;
  const int iblk = blockIdx.x * 128;
  const int head = blockIdx.y;
  const int chunk = blockIdx.z;
  const int ch = head * 64;
  const int i0 = iblk + w * 32;
  const int ji = l >> 3;
  const int sg = l & 7;
  const int r0 = w * 2;
  const int j0base = chunk * 1024;
  // Q B-fragments in registers for the whole kernel
  f16x8 qf[2][2];
#pragma unroll
  for (int nt = 0; nt < 2; ++nt) {
    const unsigned short* qr = qp + (size_t)(i0 + nt * 16 + i15) * 512 + ch;
#pragma unroll
    for (int ks = 0; ks < 2; ++ks)
      qf[nt][ks] = *(const f16x8*)(qr + ks * 32 + q4 * 8);
  }
  f32x4 oacc[4][2] = {};
  float den[2] = {0.f, 0.f};
  // ---- precomputed lane-constant LDS byte offsets
  int kfo[4][2], vfo[2][4];
#pragma unroll
  for (int mtj = 0; mtj < 4; ++mtj) {
    int js = mtj * 16 + i15;
    int h = (js & 7) ^ (js >> 3);
#pragma unroll
    for (int ksd = 0; ksd < 2; ++ksd)
      kfo[mtj][ksd] = (js * 64 + (((ksd * 4 + q4) ^ h) * 8)) * 2;
  }
#pragma unroll
  for (int ks = 0; ks < 2; ++ks)
#pragma unroll
    for (int mtd = 0; mtd < 4; ++mtd) {
      int d = mtd * 16 + i15;
      int h = (d & 7) ^ (d >> 3);
      vfo[ks][mtd] = (d * 64 + (((ks * 4 + q4) ^ h) * 8)) * 2;
    }
  int ksto0, ksto1, vsto00, vsto01, vsto10, vsto11;
  {
    int r = r0, row = r * 8 + ji;
    ksto0 = (row * 64 + ((sg ^ ji ^ r) * 8)) * 2;
    int hh = (sg >> 1) & 1;
    int kg0 = (sg >> 2) * 4 + (sg & 1) * 2;
    vsto00 = (row * 64 + ((kg0 ^ ji ^ r) * 8) + hh * 4) * 2;
    vsto01 = (row * 64 + (((kg0 + 1) ^ ji ^ r) * 8) + hh * 4) * 2;
    r = r0 + 1; row = r * 8 + ji;
    ksto1 = (row * 64 + ((sg ^ ji ^ r) * 8)) * 2;
    vsto10 = (row * 64 + ((kg0 ^ ji ^ r) * 8) + hh * 4) * 2;
    vsto11 = (row * 64 + (((kg0 + 1) ^ ji ^ r) * 8) + hh * 4) * 2;
  }
  // ---- running global pointers (advance by constant stride per tile)
  const char* kgp =
      (const char*)kp + ((size_t)(j0base + r0 * 8 + ji) * 512 + ch + sg * 8) * 2;
  const char* vgp = (const char*)(vpT + (size_t)head * 64 * N_TOK) +
                    ((size_t)(r0 * 8 + ji) * N_TOK + j0base + sg * 8) * 2;
  const char* mgp =
      (const char*)mbT + ((size_t)(chunk * 16) * N_TOK + i0 + i15) * 8;
  uint4 kst0, kst1, vst0, vst1;
  unsigned long long mwc[2], mwn[2];
  // prefetch tile 0 (+ its mask words)
  kst0 = *(const uint4*)(kgp);
  kst1 = *(const uint4*)(kgp + 8192);
  vst0 = *(const uint4*)(vgp);
  vst1 = *(const uint4*)(vgp + 65536);
  mwc[0] = *(const unsigned long long*)(mgp);
  mwc[1] = *(const unsigned long long*)(mgp + 128);
  kgp += 65536;
  vgp += 128;
  mgp += 32768;
  // 16 tiles, unrolled x2 (double-buffer base = compile-time offset).
  // Final bodies prefetch past the chunk end -- lands in adjacent mapped
  // workspace regions, loaded into regs but never consumed.
  for (int jp = 0; jp < 8; ++jp) {
    ATTN_BODY(0, mwc, mwn);
    ATTN_BODY(1, mwn, mwc);
  }
  // ---- write fp32 partials: Op[chunk][head][i][64], dp[chunk][head][i]
  float* Opc = Op + ((size_t)(chunk * 8 + head) * N_TOK) * 64;
#pragma unroll
  for (int nt = 0; nt < 2; ++nt) {
    float dn = den[nt];
    dn += __shfl_xor(dn, 16);
    dn += __shfl_xor(dn, 32);
    int row = i0 + nt * 16 + i15;
#pragma unroll
    for (int mtd = 0; mtd < 4; ++mtd)
      *(f32x4*)(Opc + (size_t)row * 64 + mtd * 16 + q4 * 4) = oacc[mtd][nt];
    if (q4 == 0) dp[(size_t)(chunk * 8 + head) * N_TOK + row] = dn;
  }
}

// ---------------- launch -----------------------------------------------------
extern "C" void kernel_launch(void* const* d_in, const int* in_sizes, int n_in,
                              void* d_out, int out_size, void* d_ws, size_t ws_size,
                              hipStream_t stream) {
  const float* q = (const float*)d_in[0];
  const float* k = (const float*)d_in[1];
  const float* v = (const float*)d_in[2];
  const int* mask = (const int*)d_in[3];
  const float* wq = (const float*)d_in[4];
  const float* bq = (const float*)d_in[5];
  const float* wk = (const float*)d_in[6];
  const float* bk = (const float*)d_in[7];
  const float* wv = (const float*)d_in[8];
  const float* bv = (const float*)d_in[9];
  const float* wo = (const float*)d_in[10];
  const float* bo = (const float*)d_in[11];

  char* ws = (char*)d_ws;
  const size_t MB = 1ull << 20;
  unsigned short* woc = (unsigned short*)(ws + 4096);     // 512 KiB
  unsigned long long* mbT = (unsigned long long*)(ws + 1 * MB);  // 2 MiB
  unsigned short* qkvp = (unsigned short*)(ws + 3 * MB);  // 12 MiB: qp,kp,vpT
  unsigned short* qc = (unsigned short*)(ws + 19 * MB);   // 4 MiB
  unsigned short* kc = (unsigned short*)(ws + 23 * MB);   // 4 MiB
  unsigned short* vc = (unsigned short*)(ws + 27 * MB);   // 4 MiB
  unsigned short* wqc = (unsigned short*)(ws + 31 * MB);  // 512 KiB
  unsigned short* wkc = (unsigned short*)(ws + 31 * MB + 512 * 1024);
  unsigned short* wvc = (unsigned short*)(ws + 32 * MB);
  float* Op = (float*)(ws + 19 * MB);                     // 32 MiB (aliases qc..)
  float* dp = (float*)(ws + 51 * MB);                     // 512 KiB

  prep_kernel<<<19968, 256, 0, stream>>>(mask, mbT, q, k, v, wq, wk, wv, wo,
                                         qc, kc, vc, wqc, wkc, wvc, woc);
  qkv_gemm_kernel<<<dim3(8, 32, 3), 256, 0, stream>>>(qc, kc, vc, wqc, wkc,
                                                      wvc, bq, bk, bv, qkvp);
  attn_kernel<<<dim3(32, 8, 4), 256, 0, stream>>>(
      qkvp, qkvp + (size_t)N_TOK * 512, qkvp + 2ull * N_TOK * 512, mbT, Op, dp);
  out_gemm_kernel<<<dim3(8, 32), 256, 0, stream>>>(Op, dp, woc, bo,
                                                   (float*)d_out);
}

// Round 9
// 221.586 us; speedup vs baseline: 1.2042x; 1.1205x over previous
//
#include <hip/hip_runtime.h>

// MultiheadAttention N=4096, d_model=512, 8 heads, d_head=64.
// fp32 inputs/output, f16 MFMA pipeline. 5-kernel pipeline = round-4 measured
// best dataflow (Op read ONCE by a separate reduce; out_gemm A = small f16 ob
// that L2 absorbs across column blocks) + round-8 prep fusion (byte-neutral):
//  prep: mask bitpack (uint4 loads + nibble-LDS repack) + fp32->f16 converts ;
//  qkv GEMM: f16 inputs, global_load_lds(16B) staging, pre-swizzled source ;
//  attn: split-KV flash attention (verified, unchanged) ;
//  reduce: split-KV combine, Op fp32 32MB read once -> ob f16 4MB ;
//  out GEMM: f16 ob x f16 woc -> fp32 out.

typedef __attribute__((ext_vector_type(8))) _Float16 f16x8;
typedef __attribute__((ext_vector_type(2))) __fp16 fp16x2_raw;  // cvt_pkrtz ret
typedef __attribute__((ext_vector_type(4))) float f32x4;

union pku_t { unsigned u[4]; f16x8 v; };

#define N_TOK 4096
#define QSCALE 0.18033688f  // 0.125 * log2(e)

__device__ __forceinline__ unsigned short f2h(float f) {
  union { _Float16 h; unsigned short u; } c;
  c.h = (_Float16)f;
  return c.u;
}
// packed f32x2 -> f16x2 in ONE instruction (v_cvt_pkrtz_f16_f32).
__device__ __forceinline__ unsigned pack_f16(float a, float b) {
  union { fp16x2_raw h; unsigned u; } c;
  c.h = __builtin_amdgcn_cvt_pkrtz(a, b);
  return c.u;
}
__device__ __forceinline__ f32x4 mfma16(f16x8 a, f16x8 b, f32x4 c) {
  return __builtin_amdgcn_mfma_f32_16x16x32_f16(a, b, c, 0, 0, 0);
}
__device__ __forceinline__ float fast_exp2(float x) {
#if __has_builtin(__builtin_amdgcn_exp2f)
  return __builtin_amdgcn_exp2f(x);
#else
  return exp2f(x);
#endif
}
// async global->LDS, 16B per lane; LDS dest is wave-uniform base + lane*16.
__device__ __forceinline__ void gload_lds16(const void* g, void* l) {
  __builtin_amdgcn_global_load_lds(
      (const __attribute__((address_space(1))) void*)g,
      (__attribute__((address_space(3))) void*)l, 16, 0, 0);
}

// ---------------- prep: mask bit-pack + fp32->f16 converts (one launch) ------
// blocks [0,16384): mask -> TRANSPOSED u64 bitsT[64 words][4096 rows].
//   uint4 load (4 int32 mask elems {0,1} per lane, 16B/lane) -> 4-bit nibble
//   -> LDS byte -> lanes 0..3/wave assemble u64 words via shift-pack.
// blocks [16384,19968): bulk convert of q,k,v (1024 blocks each) and
//   wq,wk,wv,wo (128 blocks each), 8 floats/thread.
__global__ __launch_bounds__(256) void prep_kernel(
    const int* __restrict__ m, unsigned long long* __restrict__ bitsT,
    const float* __restrict__ s0, const float* __restrict__ s1,
    const float* __restrict__ s2, const float* __restrict__ s3,
    const float* __restrict__ s4, const float* __restrict__ s5,
    const float* __restrict__ s6, unsigned short* __restrict__ d0,
    unsigned short* __restrict__ d1, unsigned short* __restrict__ d2,
    unsigned short* __restrict__ d3, unsigned short* __restrict__ d4,
    unsigned short* __restrict__ d5, unsigned short* __restrict__ d6) {
  __shared__ __align__(16) unsigned char nl[256];
  int bx = blockIdx.x;
  int t = threadIdx.x;
  if (bx < 16384) {
    // each block covers 1024 mask elems starting at bx*1024
    uint4 x = *(const uint4*)(m + (size_t)bx * 1024 + t * 4);
    unsigned nib = (x.x != 0 ? 1u : 0u) | (x.y != 0 ? 2u : 0u) |
                   (x.z != 0 ? 4u : 0u) | (x.w != 0 ? 8u : 0u);
    nl[t] = (unsigned char)nib;
    __syncthreads();
    int j = t & 63;
    if (j < 4) {
      int w = t >> 6;
      uint4 nb = *(const uint4*)(nl + w * 64 + j * 16);
      const unsigned* nd = (const unsigned*)&nb;
      unsigned long long word = 0;
#pragma unroll
      for (int d = 0; d < 4; ++d) {
        unsigned y = (nd[d] | (nd[d] >> 4)) & 0x00FF00FFu;
        y = (y | (y >> 8)) & 0x0000FFFFu;
        word |= (unsigned long long)y << (16 * d);
      }
      int eb = bx * 1024 + w * 256 + j * 64;  // first elem of this word
      int row = eb >> 12;                     // mask row
      int jw = (eb & 4095) >> 6;              // word index within row
      bitsT[(size_t)jw * N_TOK + row] = word;
    }
    return;
  }
  int b2i = bx - 16384;
  int z, blk;
  if (b2i < 3072) { z = b2i >> 10; blk = b2i & 1023; }
  else { int wb = b2i - 3072; z = 3 + (wb >> 7); blk = wb & 127; }
  const float* src = z == 0 ? s0 : z == 1 ? s1 : z == 2 ? s2 : z == 3 ? s3
                     : z == 4 ? s4 : z == 5 ? s5 : s6;
  unsigned short* dst = z == 0 ? d0 : z == 1 ? d1 : z == 2 ? d2 : z == 3 ? d3
                        : z == 4 ? d4 : z == 5 ? d5 : d6;
  int idx = (blk * 256 + t) * 8;
  float4 f0 = *(const float4*)(src + idx);
  float4 f1 = *(const float4*)(src + idx + 4);
  uint4 o;
  o.x = pack_f16(f0.x, f0.y);
  o.y = pack_f16(f0.z, f0.w);
  o.z = pack_f16(f1.x, f1.y);
  o.w = pack_f16(f1.z, f1.w);
  *(uint4*)(dst + idx) = o;
}

// ---------------- GEMM: out[n][o] = (sum_k A[n][k]*W[o][k] + bias[o])*scale --
// A,W f16 K-major. 128(m)x64(n) tile, BK=64, 4 waves 2x2 (wave = 64m x 32n).
// Staging: global_load_lds 16B/lane, linear LDS [rows][64] shorts; the 16B
// unit column is XOR-swizzled by (row&7) on the GLOBAL source so ds_reads
// (same XOR) are conflict-reduced (both-sides swizzle, m97/m173 pattern).
// TRANS=1: write f16 transposed per-head: out[h=col>>6][col&63][token].
// O32=1: write fp32 (final output).
template <int O32, int TRANS>
__device__ __forceinline__ void gemm_body64(
    const unsigned short* __restrict__ A, const unsigned short* __restrict__ W,
    const float* __restrict__ bias, void* __restrict__ out, float oscale) {
  __shared__ __align__(16) unsigned short As[128 * 64];
  __shared__ __align__(16) unsigned short Bs[64 * 64];
  const int t = threadIdx.x;
  const int lane = t & 63, w = t >> 6;
  const int wm = w & 1, wn = w >> 1;
  const int q4 = lane >> 4, i15 = lane & 15;
  const int m0 = blockIdx.y * 128, n0 = blockIdx.x * 64;
  f32x4 acc[4][2] = {};
  const int lr = lane >> 3;
  const int su = (lane & 7) ^ lr;
  const unsigned short* agp = A + (size_t)(m0 + w * 32 + lr) * 512 + su * 8;
  const unsigned short* bgp = W + (size_t)(n0 + w * 16 + lr) * 512 + su * 8;
  unsigned short* asb = As + (w * 32) * 64;
  unsigned short* bsb = Bs + (w * 16) * 64;
  const int h8 = i15 & 7;  // read-side swizzle key
  for (int k0 = 0; k0 < 512; k0 += 64) {
    __syncthreads();
#pragma unroll
    for (int i = 0; i < 4; ++i)
      gload_lds16(agp + i * 8 * 512 + k0, asb + i * 8 * 64);
#pragma unroll
    for (int i = 0; i < 2; ++i)
      gload_lds16(bgp + i * 8 * 512 + k0, bsb + i * 8 * 64);
    __syncthreads();
#pragma unroll
    for (int ks = 0; ks < 2; ++ks) {
      f16x8 af[4], bfr[2];
#pragma unroll
      for (int mt = 0; mt < 4; ++mt)
        af[mt] = *(const f16x8*)(As + (wm * 64 + mt * 16 + i15) * 64 +
                                 (((ks * 4 + q4) ^ h8) * 8));
#pragma unroll
      for (int nt = 0; nt < 2; ++nt)
        bfr[nt] = *(const f16x8*)(Bs + (wn * 32 + nt * 16 + i15) * 64 +
                                  (((ks * 4 + q4) ^ h8) * 8));
#pragma unroll
      for (int mt = 0; mt < 4; ++mt)
#pragma unroll
        for (int nt = 0; nt < 2; ++nt)
          acc[mt][nt] = mfma16(af[mt], bfr[nt], acc[mt][nt]);
    }
  }
  // epilogue: C layout col = lane&15 (+16nt+32wn), row = quad*4+reg (+16mt+64wm)
#pragma unroll
  for (int nt = 0; nt < 2; ++nt) {
    int col = n0 + wn * 32 + nt * 16 + i15;
    float bv = bias[col];
    if (TRANS) {
      unsigned short* ob_ = (unsigned short*)out +
                            (size_t)(col >> 6) * (64 * N_TOK) +
                            (size_t)(col & 63) * N_TOK;
#pragma unroll
      for (int mt = 0; mt < 4; ++mt) {
        int rowb = m0 + wm * 64 + mt * 16 + q4 * 4;
        uint2 pr;
        pr.x = pack_f16(acc[mt][nt][0] + bv, acc[mt][nt][1] + bv);
        pr.y = pack_f16(acc[mt][nt][2] + bv, acc[mt][nt][3] + bv);
        *(uint2*)(ob_ + rowb) = pr;
      }
    } else {
#pragma unroll
      for (int mt = 0; mt < 4; ++mt) {
        int rowb = m0 + wm * 64 + mt * 16 + q4 * 4;
#pragma unroll
        for (int rr = 0; rr < 4; ++rr) {
          int idx = (rowb + rr) * 512 + col;
          float val = (acc[mt][nt][rr] + bv) * oscale;
          if (O32) ((float*)out)[idx] = val;
          else ((unsigned short*)out)[idx] = f2h(val);
        }
      }
    }
  }
}

__global__ __launch_bounds__(256) void qkv_gemm_kernel(
    const unsigned short* __restrict__ qc, const unsigned short* __restrict__ kc,
    const unsigned short* __restrict__ vc, const unsigned short* __restrict__ wqc,
    const unsigned short* __restrict__ wkc, const unsigned short* __restrict__ wvc,
    const float* __restrict__ bq, const float* __restrict__ bk,
    const float* __restrict__ bv, unsigned short* __restrict__ outbase) {
  int z = blockIdx.z;
  if (z == 0) {
    gemm_body64<0, 0>(qc, wqc, bq, outbase, QSCALE);
  } else if (z == 1) {
    gemm_body64<0, 0>(kc, wkc, bk, outbase + (size_t)N_TOK * 512, 1.0f);
  } else {
    gemm_body64<0, 1>(vc, wvc, bv, outbase + 2ull * N_TOK * 512, 1.0f);
  }
}

__global__ __launch_bounds__(256) void out_gemm_kernel(
    const unsigned short* __restrict__ A, const unsigned short* __restrict__ W,
    const float* __restrict__ B, float* __restrict__ out) {
  gemm_body64<1, 0>(A, W, B, out, 1.0f);
}

// ---------------- combine split-KV partials -> f16 attention output ---------
// Op fp32 (32MB) read ONCE here; out_gemm then re-reads only the 4MB f16 ob
// (L2-resident across its 8 column blocks). This is the round-4 dataflow.
__global__ __launch_bounds__(256) void reduce_kernel(
    const float* __restrict__ Op, const float* __restrict__ dp,
    unsigned short* __restrict__ ob) {
  int x = blockIdx.x * 256 + threadIdx.x;  // 0..524287
  int i = x >> 7;
  int c = (x & 127) * 4;
  int h = c >> 6;
  int d = c & 63;
  const size_t CH = (size_t)8 * N_TOK * 64;  // floats per chunk
  size_t base = ((size_t)h * N_TOK + i) * 64 + d;
  float4 a0 = *(const float4*)(Op + base);
  float4 a1 = *(const float4*)(Op + CH + base);
  float4 a2 = *(const float4*)(Op + 2 * CH + base);
  float4 a3 = *(const float4*)(Op + 3 * CH + base);
  float den = dp[(size_t)h * N_TOK + i] + dp[(size_t)(8 + h) * N_TOK + i] +
              dp[(size_t)(16 + h) * N_TOK + i] + dp[(size_t)(24 + h) * N_TOK + i];
  float inv = 1.0f / den;
  float sx = (a0.x + a1.x + a2.x + a3.x) * inv;
  float sy = (a0.y + a1.y + a2.y + a3.y) * inv;
  float sz = (a0.z + a1.z + a2.z + a3.z) * inv;
  float sw = (a0.w + a1.w + a2.w + a3.w) * inv;
  uint2 o;
  o.x = pack_f16(sx, sy);
  o.y = pack_f16(sz, sw);
  *(uint2*)(ob + (size_t)i * 512 + c) = o;
}

// ---------------- split-KV flash attention -----------------------------------
// Block: 256 threads = 4 waves; 128 q-rows x head x 1024-j chunk (4 blocks/CU).
// Per 64-j tile: K/V staged cooperatively into double-buffered LDS, ONE
// barrier/tile. All LDS addresses precomputed per-lane (loop unrolled x2 so
// the buffer base is a compile-time offset immediate); global K/V/mask are
// running pointers. S^T = K*Q^T, p = exp2 (mask select-to--200), pack via
// v_cvt_pkrtz directly into [nt][ks] unions (PV B-frag = those regs, no
// repack), s_setprio(1) around MFMA clusters (T5), O^T += V^T*P^T.
#define ATTN_BODY(BUF, MWIN, MWOUT)                                           \
  do {                                                                        \
    char* KsB = (char*)(Ks[BUF]);                                             \
    char* VtB = (char*)(Vt[BUF]);                                             \
    *(uint4*)(KsB + ksto0) = kst0;                                            \
    *(uint4*)(KsB + ksto1) = kst1;                                            \
    {                                                                         \
      const unsigned* vs = (const unsigned*)&vst0;                            \
      *(uint2*)(VtB + vsto00) = make_uint2(vs[0], vs[1]);                     \
      *(uint2*)(VtB + vsto01) = make_uint2(vs[2], vs[3]);                     \
    }                                                                         \
    {                                                                         \
      const unsigned* vs = (const unsigned*)&vst1;                            \
      *(uint2*)(VtB + vsto10) = make_uint2(vs[0], vs[1]);                     \
      *(uint2*)(VtB + vsto11) = make_uint2(vs[2], vs[3]);                     \
    }                                                                         \
    __syncthreads();                                                          \
    kst0 = *(const uint4*)(kgp);                                              \
    kst1 = *(const uint4*)(kgp + 8192);                                       \
    vst0 = *(const uint4*)(vgp);                                              \
    vst1 = *(const uint4*)(vgp + 65536);                                      \
    MWOUT[0] = *(const unsigned long long*)(mgp);                             \
    MWOUT[1] = *(const unsigned long long*)(mgp + 128);                       \
    kgp += 65536;                                                             \
    vgp += 128;                                                               \
    mgp += 32768;                                                             \
    unsigned long long mq0 = MWIN[0] >> (q4 * 4);                             \
    unsigned long long mq1 = MWIN[1] >> (q4 * 4);                             \
    pku_t pk[2][2];                                                           \
    _Pragma("unroll") for (int mtj = 0; mtj < 4; ++mtj) {                     \
      f16x8 Kf0 = *(const f16x8*)(KsB + kfo[mtj][0]);                         \
      f16x8 Kf1 = *(const f16x8*)(KsB + kfo[mtj][1]);                         \
      _Pragma("unroll") for (int nt = 0; nt < 2; ++nt) {                      \
        f32x4 s = {0.f, 0.f, 0.f, 0.f};                                       \
        __builtin_amdgcn_s_setprio(1);                                        \
        s = mfma16(Kf0, qf[nt][0], s);                                        \
        s = mfma16(Kf1, qf[nt][1], s);                                        \
        __builtin_amdgcn_s_setprio(0);                                        \
        unsigned nib =                                                        \
            (unsigned)((nt ? mq1 : mq0) >> (mtj * 16)) & 15u;                 \
        float p0 = fast_exp2((nib & 1u) ? -200.f : s[0]);                     \
        float p1 = fast_exp2((nib & 2u) ? -200.f : s[1]);                     \
        float p2 = fast_exp2((nib & 4u) ? -200.f : s[2]);                     \
        float p3 = fast_exp2((nib & 8u) ? -200.f : s[3]);                     \
        den[nt] += (p0 + p1) + (p2 + p3);                                     \
        pk[nt][mtj >> 1].u[(mtj & 1) * 2] = pack_f16(p0, p1);                 \
        pk[nt][mtj >> 1].u[(mtj & 1) * 2 + 1] = pack_f16(p2, p3);             \
      }                                                                       \
    }                                                                         \
    __builtin_amdgcn_s_setprio(1);                                            \
    _Pragma("unroll") for (int ks = 0; ks < 2; ++ks) {                        \
      f16x8 Vf[4];                                                            \
      _Pragma("unroll") for (int mtd = 0; mtd < 4; ++mtd) Vf[mtd] =           \
          *(const f16x8*)(VtB + vfo[ks][mtd]);                                \
      _Pragma("unroll") for (int nt = 0; nt < 2; ++nt) {                      \
        _Pragma("unroll") for (int mtd = 0; mtd < 4; ++mtd) oacc[mtd][nt] =   \
            mfma16(Vf[mtd], pk[nt][ks].v, oacc[mtd][nt]);                     \
      }                                                                       \
    }                                                                         \
    __builtin_amdgcn_s_setprio(0);                                            \
  } while (0)

__global__ __launch_bounds__(256, 2) void attn_kernel(
    const unsigned short* __restrict__ qp, const unsigned short* __restrict__ kp,
    const unsigned short* __restrict__ vpT,
    const unsigned long long* __restrict__ mbT,
    float* __restrict__ Op, float* __restrict__ dp) {
  __shared__ unsigned short Ks[2][64 * 64];
  __shared__ unsigned short Vt[2][64 * 64];
  const int t = threadIdx.x;
  const int l = t & 63, w = t >> 6;
  const int q4 = l >> 4, i15 = l & 15;
  const int iblk = blockIdx.x * 128;
  const int head = blockIdx.y;
  const int chunk = blockIdx.z;
  const int ch = head * 64;
  const int i0 = iblk + w * 32;
  const int ji = l >> 3;
  const int sg = l & 7;
  const int r0 = w * 2;
  const int j0base = chunk * 1024;
  // Q B-fragments in registers for the whole kernel
  f16x8 qf[2][2];
#pragma unroll
  for (int nt = 0; nt < 2; ++nt) {
    const unsigned short* qr = qp + (size_t)(i0 + nt * 16 + i15) * 512 + ch;
#pragma unroll
    for (int ks = 0; ks < 2; ++ks)
      qf[nt][ks] = *(const f16x8*)(qr + ks * 32 + q4 * 8);
  }
  f32x4 oacc[4][2] = {};
  float den[2] = {0.f, 0.f};
  // ---- precomputed lane-constant LDS byte offsets
  int kfo[4][2], vfo[2][4];
#pragma unroll
  for (int mtj = 0; mtj < 4; ++mtj) {
    int js = mtj * 16 + i15;
    int h = (js & 7) ^ (js >> 3);
#pragma unroll
    for (int ksd = 0; ksd < 2; ++ksd)
      kfo[mtj][ksd] = (js * 64 + (((ksd * 4 + q4) ^ h) * 8)) * 2;
  }
#pragma unroll
  for (int ks = 0; ks < 2; ++ks)
#pragma unroll
    for (int mtd = 0; mtd < 4; ++mtd) {
      int d = mtd * 16 + i15;
      int h = (d & 7) ^ (d >> 3);
      vfo[ks][mtd] = (d * 64 + (((ks * 4 + q4) ^ h) * 8)) * 2;
    }
  int ksto0, ksto1, vsto00, vsto01, vsto10, vsto11;
  {
    int r = r0, row = r * 8 + ji;
    ksto0 = (row * 64 + ((sg ^ ji ^ r) * 8)) * 2;
    int hh = (sg >> 1) & 1;
    int kg0 = (sg >> 2) * 4 + (sg & 1) * 2;
    vsto00 = (row * 64 + ((kg0 ^ ji ^ r) * 8) + hh * 4) * 2;
    vsto01 = (row * 64 + (((kg0 + 1) ^ ji ^ r) * 8) + hh * 4) * 2;
    r = r0 + 1; row = r * 8 + ji;
    ksto1 = (row * 64 + ((sg ^ ji ^ r) * 8)) * 2;
    vsto10 = (row * 64 + ((kg0 ^ ji ^ r) * 8) + hh * 4) * 2;
    vsto11 = (row * 64 + (((kg0 + 1) ^ ji ^ r) * 8) + hh * 4) * 2;
  }
  // ---- running global pointers (advance by constant stride per tile)
  const char* kgp =
      (const char*)kp + ((size_t)(j0base + r0 * 8 + ji) * 512 + ch + sg * 8) * 2;
  const char* vgp = (const char*)(vpT + (size_t)head * 64 * N_TOK) +
                    ((size_t)(r0 * 8 + ji) * N_TOK + j0base + sg * 8) * 2;
  const char* mgp =
      (const char*)mbT + ((size_t)(chunk * 16) * N_TOK + i0 + i15) * 8;
  uint4 kst0, kst1, vst0, vst1;
  unsigned long long mwc[2], mwn[2];
  // prefetch tile 0 (+ its mask words)
  kst0 = *(const uint4*)(kgp);
  kst1 = *(const uint4*)(kgp + 8192);
  vst0 = *(const uint4*)(vgp);
  vst1 = *(const uint4*)(vgp + 65536);
  mwc[0] = *(const unsigned long long*)(mgp);
  mwc[1] = *(const unsigned long long*)(mgp + 128);
  kgp += 65536;
  vgp += 128;
  mgp += 32768;
  // 16 tiles, unrolled x2 (double-buffer base = compile-time offset).
  // Final bodies prefetch past the chunk end -- lands in adjacent mapped
  // workspace regions, loaded into regs but never consumed.
  for (int jp = 0; jp < 8; ++jp) {
    ATTN_BODY(0, mwc, mwn);
    ATTN_BODY(1, mwn, mwc);
  }
  // ---- write fp32 partials: Op[chunk][head][i][64], dp[chunk][head][i]
  float* Opc = Op + ((size_t)(chunk * 8 + head) * N_TOK) * 64;
#pragma unroll
  for (int nt = 0; nt < 2; ++nt) {
    float dn = den[nt];
    dn += __shfl_xor(dn, 16);
    dn += __shfl_xor(dn, 32);
    int row = i0 + nt * 16 + i15;
#pragma unroll
    for (int mtd = 0; mtd < 4; ++mtd)
      *(f32x4*)(Opc + (size_t)row * 64 + mtd * 16 + q4 * 4) = oacc[mtd][nt];
    if (q4 == 0) dp[(size_t)(chunk * 8 + head) * N_TOK + row] = dn;
  }
}

// ---------------- launch -----------------------------------------------------
extern "C" void kernel_launch(void* const* d_in, const int* in_sizes, int n_in,
                              void* d_out, int out_size, void* d_ws, size_t ws_size,
                              hipStream_t stream) {
  const float* q = (const float*)d_in[0];
  const float* k = (const float*)d_in[1];
  const float* v = (const float*)d_in[2];
  const int* mask = (const int*)d_in[3];
  const float* wq = (const float*)d_in[4];
  const float* bq = (const float*)d_in[5];
  const float* wk = (const float*)d_in[6];
  const float* bk = (const float*)d_in[7];
  const float* wv = (const float*)d_in[8];
  const float* bv = (const float*)d_in[9];
  const float* wo = (const float*)d_in[10];
  const float* bo = (const float*)d_in[11];

  char* ws = (char*)d_ws;
  const size_t MB = 1ull << 20;
  unsigned short* woc = (unsigned short*)(ws + 4096);     // 512 KiB
  unsigned long long* mbT = (unsigned long long*)(ws + 1 * MB);  // 2 MiB
  unsigned short* qkvp = (unsigned short*)(ws + 3 * MB);  // 12 MiB: qp,kp,vpT
  unsigned short* ob = (unsigned short*)(ws + 15 * MB);   // 4 MiB
  unsigned short* qc = (unsigned short*)(ws + 19 * MB);   // 4 MiB
  unsigned short* kc = (unsigned short*)(ws + 23 * MB);   // 4 MiB
  unsigned short* vc = (unsigned short*)(ws + 27 * MB);   // 4 MiB
  unsigned short* wqc = (unsigned short*)(ws + 31 * MB);  // 512 KiB
  unsigned short* wkc = (unsigned short*)(ws + 31 * MB + 512 * 1024);
  unsigned short* wvc = (unsigned short*)(ws + 32 * MB);
  float* Op = (float*)(ws + 19 * MB);                     // 32 MiB (aliases qc..)
  float* dp = (float*)(ws + 51 * MB);                     // 512 KiB

  prep_kernel<<<19968, 256, 0, stream>>>(mask, mbT, q, k, v, wq, wk, wv, wo,
                                         qc, kc, vc, wqc, wkc, wvc, woc);
  qkv_gemm_kernel<<<dim3(8, 32, 3), 256, 0, stream>>>(qc, kc, vc, wqc, wkc,
                                                      wvc, bq, bk, bv, qkvp);
  attn_kernel<<<dim3(32, 8, 4), 256, 0, stream>>>(
      qkvp, qkvp + (size_t)N_TOK * 512, qkvp + 2ull * N_TOK * 512, mbT, Op, dp);
  reduce_kernel<<<2048, 256, 0, stream>>>(Op, dp, ob);
  out_gemm_kernel<<<dim3(8, 32), 256, 0, stream>>>(ob, woc, bo, (float*)d_out);
}